// Round 1
// baseline (291.071 us; speedup 1.0000x reference)
//
#include <hip/hip_runtime.h>
#include <hip/hip_bf16.h>

#define NB     32768
#define DDIM   256
#define KNBR   16
#define ADIM   64
#define TWOD   512
#define ROWS_PB 16
#define NTHREADS 256

using bf16x8  = __attribute__((ext_vector_type(8))) short;
using short4v = __attribute__((ext_vector_type(4))) short;
using f32x4   = __attribute__((ext_vector_type(4))) float;

__device__ __forceinline__ short f2bf(float x) {
  unsigned int u;
  __builtin_memcpy(&u, &x, 4);
  u += 0x7FFFu + ((u >> 16) & 1u);   // RNE, inputs are never NaN
  return (short)(u >> 16);
}
__device__ __forceinline__ float bf2f(short s) {
  unsigned int u = ((unsigned int)(unsigned short)s) << 16;
  float f;
  __builtin_memcpy(&f, &u, 4);
  return f;
}

// B-fragment loader, direct from f32 row-major weight (mirror k-map g*8+i)
__device__ __forceinline__ bf16x8 ldWfrag(const float* __restrict__ W, int ld, int r, int c) {
  const float4* p = (const float4*)(W + (size_t)r * ld + c);
  float4 a = p[0];
  float4 b = p[1];
  bf16x8 o;
  o[0] = f2bf(a.x); o[1] = f2bf(a.y); o[2] = f2bf(a.z); o[3] = f2bf(a.w);
  o[4] = f2bf(b.x); o[5] = f2bf(b.y); o[6] = f2bf(b.z); o[7] = f2bf(b.w);
  return o;
}

// LDS layout (shorts):
//   [0,16384)      sWk   : preswizzled Wk bf16 fragments [(t*8+s)][lane][8]
//   [16384,32768)  sNbr  : per-wave neighbor tile [wave][j=16][d=256], XOR-swizzled
//   [32768,40960)  sGate : [row=16][512] bf16 (center | context), XOR-swizzled
__global__ __launch_bounds__(NTHREADS, 2)
void natt_fused(const float* __restrict__ center,
                const float* __restrict__ neigh,
                const float* __restrict__ nwts,
                const void*  __restrict__ vmask,
                const float* __restrict__ Wq, const float* __restrict__ bq,
                const float* __restrict__ Wk, const float* __restrict__ bk,
                const float* __restrict__ Wg, const float* __restrict__ bg,
                float* __restrict__ out)
{
  __shared__ __align__(16) short smem[40960];
  const int tid  = threadIdx.x;
  const int lane = tid & 63;
  const int w    = tid >> 6;
  const int n16  = lane & 15;
  const int g4   = lane >> 4;
  const int row0 = blockIdx.x * ROWS_PB;
  const unsigned char* mb = (const unsigned char*)vmask;

  // ---- valid_mask dtype detection (1-byte bool vs 4-byte int/float), wave-uniform.
  // Reading 256 bytes is in-bounds under either layout (B >= 256 elems).
  {
  }
  const unsigned char x1 = mb[lane * 4 + 1];
  const unsigned char x2 = mb[lane * 4 + 2];
  const unsigned char x3 = mb[lane * 4 + 3];
  const bool anyGe2 = __ballot((x1 >= 2) || (x2 >= 2) || (x3 >= 2)) != 0ULL;
  const bool anyNz  = __ballot(((x1 | x2) | x3) != 0) != 0ULL;
  const bool maskIsByte = anyNz && !anyGe2;   // f32 1.0f pattern sets anyGe2 -> 4-byte path

  // ---- stage center tile -> sGate[:,0:256] (bf16, swizzled) ----
  #pragma unroll
  for (int it = 0; it < 4; ++it) {
    const int row = it * 4 + w;                 // uniform per wave
    const int d   = lane * 4;
    float4 v = *(const float4*)(center + (size_t)(row0 + row) * DDIM + d);
    short4v o;
    o[0] = f2bf(v.x); o[1] = f2bf(v.y); o[2] = f2bf(v.z); o[3] = f2bf(v.w);
    *(short4v*)&smem[32768 + ((row * 512 + d) ^ ((row & 7) << 3))] = o;
  }
  // ---- stage Wk as preswizzled bf16 fragments -> sWk ----
  #pragma unroll
  for (int wl = 0; wl < 8; ++wl) {
    const int e  = wl * 2048 + tid * 8;
    const int f  = e >> 9;                      // fragment index (t*8+s)
    const int ln = (e >> 3) & 63;
    const int r  = (f >> 3) * 16 + (ln & 15);
    const int c  = (f & 7) * 32 + (ln >> 4) * 8;
    *(bf16x8*)&smem[e] = ldWfrag(Wk, DDIM, r, c);
  }
  __syncthreads();

  // ---- q-projection (each wave redundantly computes q[16][64]) ----
  f32x4 qacc[4];
  #pragma unroll
  for (int t = 0; t < 4; ++t) {
    qacc[t][0] = 0.f; qacc[t][1] = 0.f; qacc[t][2] = 0.f; qacc[t][3] = 0.f;
  }
  #pragma unroll
  for (int s = 0; s < 8; ++s) {
    bf16x8 af = *(const bf16x8*)&smem[32768 + ((n16 * 512 + s * 32 + g4 * 8) ^ ((n16 & 7) << 3))];
    #pragma unroll
    for (int t = 0; t < 4; ++t) {
      bf16x8 bfr = ldWfrag(Wq, DDIM, t * 16 + n16, s * 32 + g4 * 8);
      qacc[t] = __builtin_amdgcn_mfma_f32_16x16x32_bf16(af, bfr, qacc[t], 0, 0, 0);
    }
  }
  float qreg[4][4];   // qreg[t][r] = q[(w?)... row=(lane>>4)*4+r][16t + n16]
  #pragma unroll
  for (int t = 0; t < 4; ++t) {
    const float bqa = bq[t * 16 + n16];
    #pragma unroll
    for (int r = 0; r < 4; ++r) qreg[t][r] = qacc[t][r] + bqa;
  }

  // ---- per-wave: 4 rows, each: stage neigh -> k-proj -> softmax -> context ----
  #pragma unroll
  for (int rr = 0; rr < 4; ++rr) {
    const int rowl = w * 4 + rr;
    const size_t gr = (size_t)(row0 + rowl);

    const float4* np = (const float4*)(neigh + gr * (size_t)(KNBR * DDIM));
    #pragma unroll
    for (int j = 0; j < 16; ++j) {
      float4 v = np[j * 64 + lane];
      short4v o;
      o[0] = f2bf(v.x); o[1] = f2bf(v.y); o[2] = f2bf(v.z); o[3] = f2bf(v.w);
      *(short4v*)&smem[16384 + w * 4096 + ((j * 256 + lane * 4) ^ ((j & 7) << 3))] = o;
    }
    float wvj[16];
    #pragma unroll
    for (int j = 0; j < 16; ++j) wvj[j] = nwts[gr * KNBR + j];

    // k-projection: M=16 neighbors, N=64, K=256
    f32x4 kacc[4];
    #pragma unroll
    for (int t = 0; t < 4; ++t) {
      kacc[t][0] = 0.f; kacc[t][1] = 0.f; kacc[t][2] = 0.f; kacc[t][3] = 0.f;
    }
    #pragma unroll
    for (int s = 0; s < 8; ++s) {
      bf16x8 af = *(const bf16x8*)&smem[16384 + w * 4096 +
                    ((n16 * 256 + s * 32 + g4 * 8) ^ ((n16 & 7) << 3))];
      #pragma unroll
      for (int t = 0; t < 4; ++t) {
        bf16x8 bfr = *(const bf16x8*)&smem[(t * 8 + s) * 512 + lane * 8];
        kacc[t] = __builtin_amdgcn_mfma_f32_16x16x32_bf16(af, bfr, kacc[t], 0, 0, 0);
      }
    }
    #pragma unroll
    for (int t = 0; t < 4; ++t) {
      const float bka = bk[t * 16 + n16];
      #pragma unroll
      for (int r = 0; r < 4; ++r) kacc[t][r] += bka;
    }

    // logits: lane holds k[j=(g4)*4+r][a=16t+n16]; q broadcast via shfl, reduce over a
    float part[4] = {0.f, 0.f, 0.f, 0.f};
    #pragma unroll
    for (int t = 0; t < 4; ++t) {
      const float qv = __shfl(qreg[t][rr], w * 16 + n16);
      #pragma unroll
      for (int r = 0; r < 4; ++r) part[r] += qv * kacc[t][r];
    }
    #pragma unroll
    for (int off = 1; off < 16; off <<= 1) {
      #pragma unroll
      for (int r = 0; r < 4; ++r) part[r] += __shfl_xor(part[r], off);
    }
    float att[16];
    float mx = -1e30f;
    #pragma unroll
    for (int j = 0; j < 16; ++j) {
      att[j] = 0.125f * __shfl(part[j & 3], (j >> 2) << 4);   // SCALE = 64^-0.5
      mx = fmaxf(mx, att[j]);
    }
    float sum = 0.f;
    #pragma unroll
    for (int j = 0; j < 16; ++j) { att[j] = __expf(att[j] - mx); sum += att[j]; }
    const float rs = 1.f / sum;
    float den = 1e-8f;
    #pragma unroll
    for (int j = 0; j < 16; ++j) { att[j] = att[j] * rs * wvj[j]; den += att[j]; }
    const float rd = 1.f / den;

    // context: lane owns dims lane*4..+3
    float cx[4] = {0.f, 0.f, 0.f, 0.f};
    #pragma unroll
    for (int j = 0; j < 16; ++j) {
      short4v nv = *(const short4v*)&smem[16384 + w * 4096 +
                     ((j * 256 + lane * 4) ^ ((j & 7) << 3))];
      const float aj = att[j];
      cx[0] += aj * bf2f(nv[0]);
      cx[1] += aj * bf2f(nv[1]);
      cx[2] += aj * bf2f(nv[2]);
      cx[3] += aj * bf2f(nv[3]);
    }
    short4v co;
    co[0] = f2bf(cx[0] * rd); co[1] = f2bf(cx[1] * rd);
    co[2] = f2bf(cx[2] * rd); co[3] = f2bf(cx[3] * rd);
    *(short4v*)&smem[32768 + ((rowl * 512 + 256 + lane * 4) ^ ((rowl & 7) << 3))] = co;
  }
  __syncthreads();

  // ---- gate GEMM (M=16 rows, N=256, K=512) + fused epilogue ----
  #pragma unroll
  for (int tt = 0; tt < 4; ++tt) {
    const int dout = (w * 4 + tt) * 16 + n16;
    f32x4 gacc;
    gacc[0] = 0.f; gacc[1] = 0.f; gacc[2] = 0.f; gacc[3] = 0.f;
    #pragma unroll
    for (int s = 0; s < 16; ++s) {
      bf16x8 af = *(const bf16x8*)&smem[32768 +
                    ((n16 * 512 + s * 32 + g4 * 8) ^ ((n16 & 7) << 3))];
      bf16x8 bfr = ldWfrag(Wg, TWOD, dout, s * 32 + g4 * 8);
      gacc = __builtin_amdgcn_mfma_f32_16x16x32_bf16(af, bfr, gacc, 0, 0, 0);
    }
    const float bga = bg[dout];
    #pragma unroll
    for (int r = 0; r < 4; ++r) {
      const int rowl = g4 * 4 + r;
      const size_t gr = (size_t)(row0 + rowl);
      const float pre  = gacc[r] + bga;
      const float gate = 1.f / (1.f + __expf(-pre));
      const float cen  = center[gr * DDIM + dout];
      const float cxv  = bf2f(smem[32768 + ((rowl * 512 + 256 + dout) ^ ((rowl & 7) << 3))]);
      const float fused = gate * cen + (1.f - gate) * cxv;
      const bool valid = maskIsByte ? (mb[gr] != 0)
                                    : (((const unsigned int*)vmask)[gr] != 0u);
      out[gr * DDIM + dout] = valid ? fused : cen;
    }
  }
}

extern "C" void kernel_launch(void* const* d_in, const int* in_sizes, int n_in,
                              void* d_out, int out_size, void* d_ws, size_t ws_size,
                              hipStream_t stream) {
  const float* center = (const float*)d_in[0];
  const float* neigh  = (const float*)d_in[1];
  const float* nwts   = (const float*)d_in[2];
  const void*  vm     = d_in[3];
  const float* Wq = (const float*)d_in[4];
  const float* bq = (const float*)d_in[5];
  const float* Wk = (const float*)d_in[6];
  const float* bk = (const float*)d_in[7];
  const float* Wg = (const float*)d_in[8];
  const float* bg = (const float*)d_in[9];
  float* out = (float*)d_out;

  const int nrows = in_sizes[0] / DDIM;           // 32768
  dim3 grid(nrows / ROWS_PB), block(NTHREADS);
  hipLaunchKernelGGL(natt_fused, grid, block, 0, stream,
                     center, neigh, nwts, vm, Wq, bq, Wk, bk, Wg, bg, out);
}